// Round 2
// 141.414 us; speedup vs baseline: 1.0024x; 1.0024x over previous
//
#include <hip/hip_runtime.h>

constexpr int B_DIM = 256, T_DIM = 8192;
constexpr long long GATE_N = (long long)B_DIM * 2 * T_DIM;   // 4,194,304
constexpr long long EXT_N  = GATE_N * 5;                     // 20,971,520

// Native 16B vector type: __builtin_nontemporal_store requires a real vector
// type, not HIP's float4 class.
typedef float f4 __attribute__((ext_vector_type(4)));

// Single fused kernel. The uniform breath@temple fold (formerly temple_setup)
// is computed once per block by thread 0 into LDS (88 B) — removes one kernel
// launch + the global-memory w dependency that serialized the graph.
__global__ __launch_bounds__(256) void temple_fused(const float* __restrict__ x,
                                                    const float* __restrict__ temple,
                                                    const float* __restrict__ breath,
                                                    float* __restrict__ out) {
    __shared__ double w[11];
    const int k  = threadIdx.x;
    const int b  = blockIdx.x >> 5;            // 32 blocks per b-row
    const int t0 = (blockIdx.x & 31) << 8;     // 256 items per block
    const long long rowBase = (long long)b * (2 * T_DIM);
    float* gate = out;
    float* ext  = out + GATE_N;

    // ---- issue ALL global loads first; none depend on w ----
    const f4* __restrict__ src4 = (const f4*)(x + ((long long)b * T_DIM + t0) * 5);
    const bool extra = (k < 64);               // exactly wave 0: no intra-wave divergence
    f4 c0 = src4[k];
    f4 c1 = {};
    if (extra) c1 = src4[256 + k];

    const int t = t0 + k;
    const float* __restrict__ xi = x + ((long long)b * T_DIM + t) * 5;
    const float x0 = xi[0], x1 = xi[1], x2 = xi[2], x3 = xi[3], x4 = xi[4];

    // ---- main-half copy is mode-independent: store before the barrier ----
    // nt: 100 MB streaming writes have zero reuse; don't pollute 32 MB L2.
    f4* dmain = (f4*)(ext + (rowBase + t0) * 5);
    __builtin_nontemporal_store(c0, dmain + k);
    if (extra) __builtin_nontemporal_store(c1, dmain + 256 + k);

    // ---- per-block uniform fold (bit-identical op order to old temple_setup) ----
    if (k == 0) {
        double s = 0.0;
        for (int d = 0; d < 5; ++d) s += (double)x[d];
        s = s / 5.0;
        double seed  = s - floor(s);
        double chaos = 3.5699456 * seed * (1.0 - seed);
        int mode = (chaos > 0.7) ? 0 : ((chaos > 0.4) ? 1 : 2);
        for (int d = 0; d < 5; ++d) {
            double a = 0.0, c = 0.0;
            for (int r = 0; r < 4; ++r) {
                double tv = (double)temple[r * 5 + d];
                a += (double)breath[r]     * tv;   // breath_main = breath[0:4]
                c += (double)breath[r + 1] * tv;   // breath_mirror = breath[1:5]
            }
            w[d] = a; w[5 + d] = c;
        }
        w[10] = (double)mode;
        if (blockIdx.x == 0) out[GATE_N + EXT_N] = (float)mode;
    }
    __syncthreads();
    const int mode = (int)w[10];               // LDS broadcast, conflict-free

    // ---- mirror-half copy (mode-dependent) ----
    if (mode == 0) {
        f4* dmir = (f4*)(ext + (rowBase + T_DIM + t0) * 5);
        f4 m0; m0.x = 9.f - c0.x; m0.y = 9.f - c0.y; m0.z = 9.f - c0.z; m0.w = 9.f - c0.w;
        __builtin_nontemporal_store(m0, dmir + k);
        if (extra) {
            f4 m1; m1.x = 9.f - c1.x; m1.y = 9.f - c1.y; m1.z = 9.f - c1.z; m1.w = 9.f - c1.w;
            __builtin_nontemporal_store(m1, dmir + 256 + k);
        }
    } else if (mode == 2) {
        f4* dmir = (f4*)(ext + (rowBase + T_DIM + t0) * 5);
        __builtin_nontemporal_store(c0, dmir + k);
        if (extra) __builtin_nontemporal_store(c1, dmir + 256 + k);
    } else {                                   // flip: owner writes mirrored address
        float* dm = ext + (rowBase + 2 * T_DIM - 1 - t) * 5;
        __builtin_nontemporal_store(x0, dm + 0);
        __builtin_nontemporal_store(x1, dm + 1);
        __builtin_nontemporal_store(x2, dm + 2);
        __builtin_nontemporal_store(x3, dm + 3);
        __builtin_nontemporal_store(x4, dm + 4);
    }

    // ---- two interleaved f64 scan chains (bit-identical math to prior rounds) ----
    const double wa0 = w[0], wa1 = w[1], wa2 = w[2], wa3 = w[3], wa4 = w[4];
    const double wb0 = w[5], wb1 = w[6], wb2 = w[7], wb3 = w[8], wb4 = w[9];
    double a0 = x0, a1 = x1, a2 = x2, a3 = x3, a4 = x4;
    double b0, b1, b2, b3, b4;
    if (mode == 0) { b0 = 9.0 - a0; b1 = 9.0 - a1; b2 = 9.0 - a2; b3 = 9.0 - a3; b4 = 9.0 - a4; }
    else           { b0 = a0; b1 = a1; b2 = a2; b3 = a3; b4 = a4; }

    float ha[10], hb[10];
#pragma unroll
    for (int s = 0; s < 10; ++s) {
        double ra = a0 * wa0;
        ra = fma(a1, wa1, ra); ra = fma(a2, wa2, ra); ra = fma(a3, wa3, ra); ra = fma(a4, wa4, ra);
        double rb = b0 * wb0;
        rb = fma(b1, wb1, rb); rb = fma(b2, wb2, rb); rb = fma(b3, wb3, rb); rb = fma(b4, wb4, rb);
        ha[s] = (float)ra; hb[s] = (float)rb;
        double qa = floor(ra * 0.1), ma = fma(qa, -10.0, ra);
        ma = (ma < 0.0) ? ma + 10.0 : ma;  ma = (ma >= 10.0) ? ma - 10.0 : ma;
        double qb = floor(rb * 0.1), mb = fma(qb, -10.0, rb);
        mb = (mb < 0.0) ? mb + 10.0 : mb;  mb = (mb >= 10.0) ? mb - 10.0 : mb;
        a4 = a3; a3 = a2; a2 = a1; a1 = a0; a0 = ma;
        b4 = b3; b3 = b2; b2 = b1; b1 = b0; b0 = mb;
    }
    float meanA = 0.f, meanB = 0.f;
#pragma unroll
    for (int s = 0; s < 10; ++s) { meanA += ha[s]; meanB += hb[s]; }
    meanA *= 0.1f; meanB *= 0.1f;
    float ssdA = 0.f, ssdB = 0.f;
#pragma unroll
    for (int s = 0; s < 10; ++s) {
        float da = ha[s] - meanA; ssdA = fmaf(da, da, ssdA);
        float db = hb[s] - meanB; ssdB = fmaf(db, db, ssdB);
    }
    const float gm = 1.0f / (1.0f + sqrtf(ssdA * (1.0f / 9.0f)));
    const float gx = 1.0f / (1.0f + sqrtf(ssdB * (1.0f / 9.0f)));

    __builtin_nontemporal_store(gm, &gate[rowBase + t]);
    if (mode == 1) __builtin_nontemporal_store(gx, &gate[rowBase + 2 * T_DIM - 1 - t]);
    else           __builtin_nontemporal_store(gx, &gate[rowBase + T_DIM + t]);
}

extern "C" void kernel_launch(void* const* d_in, const int* in_sizes, int n_in,
                              void* d_out, int out_size, void* d_ws, size_t ws_size,
                              hipStream_t stream) {
    const float* x      = (const float*)d_in[0];   // (256, 8192, 5) f32
    const float* temple = (const float*)d_in[1];   // (4, 5) f32
    const float* breath = (const float*)d_in[2];   // (5,) f32
    float* out = (float*)d_out;                    // [gate | extended_x | mode_code]

    const int blocks = (B_DIM * T_DIM) / 256;      // 8192
    temple_fused<<<blocks, 256, 0, stream>>>(x, temple, breath, out);
}